// Round 8
// baseline (798.479 us; speedup 1.0000x reference)
//
#include <hip/hip_runtime.h>
#include <cstdint>
#include <cstddef>

using u16 = unsigned short;
using f32x4 = __attribute__((ext_vector_type(4))) float;
using bf8   = __attribute__((ext_vector_type(8))) short;   // 8 bf16 in 4 VGPRs
using u32x4 = __attribute__((ext_vector_type(4))) unsigned;

#define DEVFN __device__ __forceinline__

constexpr int BB  = 2;
constexpr int LQ  = 2048;
constexpr int LKV = 4096;
constexpr int DD  = 2048;
constexpr int NH  = 16;
constexpr int HDm = 128;
constexpr float ATTN_SCALE = 0.08838834764831845f;  // 128^-0.5
constexpr float LN_EPS = 1e-6f;
// softmax fixed shift: LN guarantees |s| <= ||q*scale||*||k|| = 1*sqrt(128) ~ 11.4
constexpr float LOG2E  = 1.4426950408889634f;
constexpr float SHIFT2 = 17.312340490667562f;       // 12.0 * log2(e)

DEVFN u16 f2bf(float f) {
  unsigned u = __builtin_bit_cast(unsigned, f);
  u += 0x7fffu + ((u >> 16) & 1u);          // RNE
  return (u16)(u >> 16);
}
DEVFN float bf2f(u16 h) { return __builtin_bit_cast(float, (unsigned)h << 16); }
DEVFN f32x4 mfma16(bf8 a, bf8 b, f32x4 c) {
  return __builtin_amdgcn_mfma_f32_16x16x32_bf16(a, b, c, 0, 0, 0);
}
// async global->LDS, 16B/lane, lane i lands at lds + i*16 (wave-uniform lds base)
DEVFN void gl16(const void* g, void* l) {
  __builtin_amdgcn_global_load_lds(
      (const __attribute__((address_space(1))) void*)g,
      (__attribute__((address_space(3))) void*)l, 16, 0, 0);
}
DEVFN void barrier_hard() {                 // raw barrier + scheduler fence
  __builtin_amdgcn_s_barrier();
  __builtin_amdgcn_sched_barrier(0);
}

// ---------------- f32 -> bf16 convert (4 el/thread) ----------------
__global__ __launch_bounds__(256) void k_cvt(const float4* __restrict__ in,
                                             ushort4* __restrict__ out, int n4) {
  int i = blockIdx.x * 256 + threadIdx.x;
  if (i >= n4) return;
  float4 v = in[i];
  ushort4 o;
  o.x = f2bf(v.x); o.y = f2bf(v.y); o.z = f2bf(v.z); o.w = f2bf(v.w);
  out[i] = o;
}

// ---------------- bf16 NT GEMM, phase-lockstep 256x128 tile ----------------
// BM=256, BN=128, BK=64; 8 waves (512 thr) as 4M x 2N, per-wave 64x64 out.
// LDS: A dbuf 64K + B dbuf 32K (+4K LN sums) -> 1 block/CU, 2 waves/SIMD.
// Per K-tile: 2 phases x 16 MFMA, per-phase {ds_read | barrier | lgkm |
// setprio MFMA | barrier}; prefetch issued at phase-1 top, ONE vmcnt(0) per
// K-tile (loads in flight across both phases). XOR swizzle throughout.
// MODE: 1 = f32 out (nontemporal); 2 = bf16 + per-head LN;
//       3 = bf16 + per-head LN + ATTN_SCALE;
//       4 = bf16 TRANSPOSED per-head out -> Y[bh][hd][kv]  (fused V-transpose)
template <int MODE>
__global__ __launch_bounds__(512) void k_gemm_nt(const u16* __restrict__ X,
                                                 const u16* __restrict__ Wt,
                                                 const float* __restrict__ bias,
                                                 const float* __restrict__ lng,
                                                 const float* __restrict__ lnb,
                                                 void* __restrict__ Y,
                                                 int M, int N, int K) {
  __shared__ __align__(16) u16 As_[2][256 * 64];   // 64 KB (reused as T in MODE4)
  __shared__ __align__(16) u16 Bs_[2][128 * 64];   // 32 KB
  __shared__ float Sm[2][256], Sq[2][256];
  const int tid = threadIdx.x;
  const int w = tid >> 6, l = tid & 63;
  const int m0 = blockIdx.x * 256, n0 = blockIdx.y * 128;
  const int wr = w >> 1, wc = w & 1;              // 4M x 2N wave grid
  const int lr = l & 15, lk = (l >> 4) * 8;
  const int rsw = (l & 7) << 3;                   // read-side swizzle (u16 units)
  const int srow = l >> 3;                        // staging: 8 lanes/row
  const int scb = (l & 7) * 16;
  f32x4 acc[4][4] = {};

  auto stage = [&](int buf, int k0) {             // 6 gl16/wave per K-tile
#pragma unroll
    for (int i = 0; i < 4; ++i) {                 // A: 256 rows
      int rbase = i * 64 + w * 8;
      int row = rbase + srow;
      int cb = scb ^ ((row & 7) << 4);            // inverse-swizzled source col
      gl16((const char*)&X[(size_t)(m0 + row) * K + k0] + cb, &As_[buf][rbase * 64]);
    }
#pragma unroll
    for (int i = 0; i < 2; ++i) {                 // B: 128 rows
      int rbase = i * 64 + w * 8;
      int row = rbase + srow;
      int cb = scb ^ ((row & 7) << 4);
      gl16((const char*)&Wt[(size_t)(n0 + row) * K + k0] + cb, &Bs_[buf][rbase * 64]);
    }
  };

  const int NT = K >> 6;
  stage(0, 0);
  asm volatile("s_waitcnt vmcnt(0)" ::: "memory");
  barrier_hard();
  for (int kt = 0; kt < NT; ++kt) {
    const int cur = kt & 1;
    // ---- phase 1: prefetch issue + A-frags + B-frags(ni 0,1) + 16 MFMA
    if (kt + 1 < NT) stage(cur ^ 1, (kt + 1) * 64);
    bf8 af[4][2], bf01[2][2];
#pragma unroll
    for (int mi = 0; mi < 4; ++mi)
#pragma unroll
      for (int kk = 0; kk < 2; ++kk)
        af[mi][kk] = *(const bf8*)&As_[cur][(wr * 64 + mi * 16 + lr) * 64 + ((kk * 32 + lk) ^ rsw)];
#pragma unroll
    for (int ni = 0; ni < 2; ++ni)
#pragma unroll
      for (int kk = 0; kk < 2; ++kk)
        bf01[ni][kk] = *(const bf8*)&Bs_[cur][(wc * 64 + ni * 16 + lr) * 64 + ((kk * 32 + lk) ^ rsw)];
    __builtin_amdgcn_s_barrier();                 // lockstep
    asm volatile("s_waitcnt lgkmcnt(0)" ::: "memory");
    __builtin_amdgcn_sched_barrier(0);
    __builtin_amdgcn_s_setprio(1);
#pragma unroll
    for (int kk = 0; kk < 2; ++kk)
#pragma unroll
      for (int mi = 0; mi < 4; ++mi)
#pragma unroll
        for (int ni = 0; ni < 2; ++ni)
          acc[mi][ni] = mfma16(af[mi][kk], bf01[ni][kk], acc[mi][ni]);
    __builtin_amdgcn_s_setprio(0);
    __builtin_amdgcn_s_barrier();
    // ---- phase 2: B-frags(ni 2,3) + 16 MFMA; vmcnt once per K-tile
    bf8 bf23[2][2];
#pragma unroll
    for (int ni = 0; ni < 2; ++ni)
#pragma unroll
      for (int kk = 0; kk < 2; ++kk)
        bf23[ni][kk] = *(const bf8*)&Bs_[cur][(wc * 64 + (ni + 2) * 16 + lr) * 64 + ((kk * 32 + lk) ^ rsw)];
    asm volatile("s_waitcnt lgkmcnt(0)" ::: "memory");
    __builtin_amdgcn_sched_barrier(0);
    __builtin_amdgcn_s_setprio(1);
#pragma unroll
    for (int kk = 0; kk < 2; ++kk)
#pragma unroll
      for (int mi = 0; mi < 4; ++mi)
#pragma unroll
        for (int ni = 0; ni < 2; ++ni)
          acc[mi][ni + 2] = mfma16(af[mi][kk], bf23[ni][kk], acc[mi][ni + 2]);
    __builtin_amdgcn_s_setprio(0);
    asm volatile("s_waitcnt vmcnt(0)" ::: "memory");   // next tile staged
    barrier_hard();
  }
  const int lrg = (l >> 4) * 4;

  // bias (pre-LN, matching reference: LN(x@W^T + b))
  float bv[4];
#pragma unroll
  for (int ni = 0; ni < 4; ++ni) bv[ni] = bias[n0 + wc * 64 + ni * 16 + lr];
#pragma unroll
  for (int mi = 0; mi < 4; ++mi)
#pragma unroll
    for (int ni = 0; ni < 4; ++ni)
#pragma unroll
      for (int r = 0; r < 4; ++r) acc[mi][ni][r] += bv[ni];

  if constexpr (MODE == 2 || MODE == 3) {
    // per-row sums over wave's 64 cols -> LDS -> combine across wc (head=128)
#pragma unroll
    for (int mi = 0; mi < 4; ++mi) {
#pragma unroll
      for (int r = 0; r < 4; ++r) {
        float ps = 0.f, pq = 0.f;
#pragma unroll
        for (int ni = 0; ni < 4; ++ni) {
          float v = acc[mi][ni][r];
          ps += v; pq += v * v;
        }
#pragma unroll
        for (int m = 1; m < 16; m <<= 1) {
          ps += __shfl_xor(ps, m);
          pq += __shfl_xor(pq, m);
        }
        if (lr == 0) {
          int rl = wr * 64 + mi * 16 + lrg + r;
          Sm[wc][rl] = ps; Sq[wc][rl] = pq;
        }
      }
    }
    __syncthreads();
    float gv[4], bbv[4];
#pragma unroll
    for (int ni = 0; ni < 4; ++ni) {
      int c = wc * 64 + ni * 16 + lr;              // col within head (BN==head)
      gv[ni] = lng[c]; bbv[ni] = lnb[c];
    }
#pragma unroll
    for (int mi = 0; mi < 4; ++mi)
#pragma unroll
      for (int r = 0; r < 4; ++r) {
        int rl = wr * 64 + mi * 16 + lrg + r;
        float mean = (Sm[0][rl] + Sm[1][rl]) * (1.f / 128.f);
        float var  = (Sq[0][rl] + Sq[1][rl]) * (1.f / 128.f) - mean * mean;
        float rs = rsqrtf(var + LN_EPS);
#pragma unroll
        for (int ni = 0; ni < 4; ++ni) {
          float o = (acc[mi][ni][r] - mean) * rs * gv[ni] + bbv[ni];
          if (MODE == 3) o *= ATTN_SCALE;
          acc[mi][ni][r] = o;
        }
      }
  }

  if constexpr (MODE == 4) {
    // fused V-transpose: stage 256x128 bf16 tile in LDS (swizzled cols),
    // then write Y[bh][hd][kv] coalesced along kv.
    u16* T = &As_[0][0];                           // 256*128 u16 = 64 KB
    __syncthreads();                               // loop LDS fully consumed
#pragma unroll
    for (int mi = 0; mi < 4; ++mi)
#pragma unroll
      for (int ni = 0; ni < 4; ++ni)
#pragma unroll
        for (int r = 0; r < 4; ++r) {
          int mrow = wr * 64 + mi * 16 + lrg + r;  // kv within tile (0..255)
          int ncol = wc * 64 + ni * 16 + lr;       // hd (0..127)
          T[mrow * 128 + (ncol ^ ((mrow & 7) << 3))] = f2bf(acc[mi][ni][r]);
        }
    __syncthreads();
    int hd = tid >> 2, q4 = tid & 3;               // hd 0..127, kv quarter
    int bq = m0 >> 12;                             // m = b*LKV + kv, LKV=4096
    int kvb = (m0 & (LKV - 1)) + q4 * 64;
    int hh = n0 >> 7;                              // n-tile == head
    u16* vout = (u16*)Y + ((size_t)(bq * NH + hh) * HDm + hd) * LKV + kvb;
#pragma unroll
    for (int j8 = 0; j8 < 8; ++j8) {
      u16 tmp[8] __attribute__((aligned(16)));
#pragma unroll
      for (int j = 0; j < 8; ++j) {
        int kv = q4 * 64 + j8 * 8 + j;
        tmp[j] = T[kv * 128 + (hd ^ ((kv & 7) << 3))];
      }
      *(int4*)&vout[j8 * 8] = *(const int4*)tmp;
    }
    return;
  }

#pragma unroll
  for (int ni = 0; ni < 4; ++ni) {
    int n = n0 + wc * 64 + ni * 16 + lr;
#pragma unroll
    for (int mi = 0; mi < 4; ++mi) {
      int mb = m0 + wr * 64 + mi * 16 + lrg;
#pragma unroll
      for (int r = 0; r < 4; ++r) {
        float v = acc[mi][ni][r];
        if constexpr (MODE == 1)
          __builtin_nontemporal_store(v, &((float*)Y)[(size_t)(mb + r) * N + n]);
        else
          ((u16*)Y)[(size_t)(mb + r) * N + n] = f2bf(v);
      }
    }
  }
}

// ---------------- fused attention (swapped QK, 32 q-rows per wave) ---------
// 256 threads / 4 waves, q-tile 128 (each wave owns 32 q rows via qc=0,1).
// LDS: Ks dbuf 32K + Vs dbuf 32K = 64KB -> 2 blocks/CU. Counted vmcnt keeps
// Wout stores in flight across barriers. Fixed softmax shift; P in registers.
__global__ __launch_bounds__(256) void k_attn(const u16* __restrict__ Qp,
                                              const u16* __restrict__ Kp,
                                              const u16* __restrict__ Vt,
                                              float* __restrict__ Wout,
                                              u16* __restrict__ AO) {
  const int g = blockIdx.x;                 // 512 blocks, 8 XCDs, 64 each
  const int work = (g & 7) * 64 + (g >> 3);
  const int bh = work >> 4;
  const int b = bh >> 4, h = bh & 15;
  const int q0 = (work & 15) * 128;
  const int tid = threadIdx.x, w = tid >> 6, l = tid & 63;
  const int lr = l & 15, lk = (l >> 4) * 8;
  const int gq = l >> 4;                    // lane group 0..3 (kv sub-quad)
  const int rsw = (l & 7) << 3;             // read swizzle, u16 units
  __shared__ __align__(16) u16 Ks[2][64 * 128];
  __shared__ __align__(16) u16 Vs[2][128 * 64];

  // Q fragments for 32 q-rows: qc half 0/1 (B-frag: col = lr)
  bf8 qf[2][4];
#pragma unroll
  for (int qc = 0; qc < 2; ++qc) {
    const u16* qb = &Qp[((size_t)b * LQ + q0 + w * 32 + qc * 16 + lr) * DD + h * HDm];
#pragma unroll
    for (int kc = 0; kc < 4; ++kc) qf[qc][kc] = *(const bf8*)(qb + kc * 32 + lk);
  }
  const u16* Kb = Kp + (size_t)b * LKV * DD + h * HDm;   // row stride DD
  const u16* Vb = Vt + (size_t)bh * HDm * LKV;           // row (hd) stride LKV

  // ---- staging (4 waves): K 64x256B -> 4 calls; V 128x128B -> 4 calls
  auto stageK = [&](int buf, int kv0) {
#pragma unroll
    for (int i = 0; i < 4; ++i) {
      int rbase = w * 16 + i * 4;
      int row = rbase + (l >> 4);
      int cb = ((l & 15) * 16) ^ ((row & 7) << 4);
      gl16((const char*)(Kb + (size_t)(kv0 + row) * DD) + cb, &Ks[buf][rbase * 128]);
    }
  };
  auto stageV = [&](int buf, int kv0) {
#pragma unroll
    for (int i = 0; i < 4; ++i) {
      int rbase = w * 32 + i * 8;
      int row = rbase + (l >> 3);
      int cb = ((l & 7) * 16) ^ ((row & 7) << 4);
      gl16((const char*)(Vb + (size_t)row * LKV + kv0) + cb, &Vs[buf][rbase * 64]);
    }
  };
  auto stageK128 = [&](u16* buf, int kv0) {   // 128 rows x 256B into 32KB region
#pragma unroll
    for (int i = 0; i < 8; ++i) {
      int rbase = w * 32 + i * 4;
      int row = rbase + (l >> 4);
      int cb = ((l & 15) * 16) ^ ((row & 7) << 4);
      gl16((const char*)(Kb + (size_t)(kv0 + row) * DD) + cb, &buf[rbase * 128]);
    }
  };

  // ================= pass A: row sums of exp2(s*log2e - SHIFT2) ============
  u16* bufA0 = &Ks[0][0];                    // 32KB = 128 rows x 128 u16
  u16* bufA1 = &Vs[0][0];
  float lsum[2] = {0.f, 0.f};
  stageK128(bufA0, 0);
  asm volatile("s_waitcnt vmcnt(0)" ::: "memory");
  barrier_hard();
  for (int t = 0; t < 32; ++t) {
    const u16* kb = (t & 1) ? bufA1 : bufA0;
    if (t < 31) stageK128((t & 1) ? bufA0 : bufA1, (t + 1) * 128);
#pragma unroll
    for (int ni = 0; ni < 8; ++ni) {
      f32x4 s0 = {0.f, 0.f, 0.f, 0.f}, s1 = {0.f, 0.f, 0.f, 0.f};
      __builtin_amdgcn_s_setprio(1);
#pragma unroll
      for (int kc = 0; kc < 4; ++kc) {
        bf8 kf = *(const bf8*)&kb[(ni * 16 + lr) * 128 + ((kc * 32 + lk) ^ rsw)];
        s0 = mfma16(kf, qf[0][kc], s0);
        s1 = mfma16(kf, qf[1][kc], s1);
      }
      __builtin_amdgcn_s_setprio(0);
#pragma unroll
      for (int r = 0; r < 4; ++r) {
        lsum[0] += exp2f(fmaf(s0[r], LOG2E, -SHIFT2));
        lsum[1] += exp2f(fmaf(s1[r], LOG2E, -SHIFT2));
      }
    }
    asm volatile("s_waitcnt vmcnt(0)" ::: "memory");  // next tile staged
    barrier_hard();
  }
  // lane lr holds partials of q-row (qc*16+lr); combine the 4 lane-groups
  float cr[2];
#pragma unroll
  for (int qc = 0; qc < 2; ++qc) {
    float v = lsum[qc];
    v += __shfl_xor(v, 16);
    v += __shfl_xor(v, 32);
    cr[qc] = -(SHIFT2 + __log2f(v));         // exp2(s*log2e + cr) = p/sum
  }

  // ================= pass B: weights + PV, kv-tile 64 =======================
  f32x4 oacc[2][8] = {};
  float* wq0 = Wout + ((size_t)bh * LQ + q0 + w * 32 + lr) * LKV;
  float* wq1 = wq0 + (size_t)16 * LKV;
  const int srcA = lr + ((gq & 1) << 5);
  const int srcB = srcA + 16;
  const bool hi = (gq >> 1) != 0;

  stageK(0, 0); stageV(0, 0);
  asm volatile("s_waitcnt vmcnt(0)" ::: "memory");
  barrier_hard();
  for (int t = 0; t < 64; ++t) {
    const int cur = t & 1;
    const int kv0 = t * 64;
    if (t < 63) { stageK(cur ^ 1, kv0 + 64); stageV(cur ^ 1, kv0 + 64); }
    // QK swapped: s[qc][ni] rows = kv (ni*16 + 4*gq + r), col = q-row qc*16+lr
    f32x4 s[2][4];
    __builtin_amdgcn_s_setprio(1);
#pragma unroll
    for (int ni = 0; ni < 4; ++ni) {
      s[0][ni] = f32x4{0.f, 0.f, 0.f, 0.f};
      s[1][ni] = f32x4{0.f, 0.f, 0.f, 0.f};
#pragma unroll
      for (int kc = 0; kc < 4; ++kc) {
        bf8 kf = *(const bf8*)&Ks[cur][(ni * 16 + lr) * 128 + ((kc * 32 + lk) ^ rsw)];
        s[0][ni] = mfma16(kf, qf[0][kc], s[0][ni]);
        s[1][ni] = mfma16(kf, qf[1][kc], s[1][ni]);
      }
    }
    __builtin_amdgcn_s_setprio(0);
    // normalized p: 4 contiguous kv per lane -> f32x4 nontemporal stores
    unsigned pk2[2][4][2];
#pragma unroll
    for (int qc = 0; qc < 2; ++qc) {
      float* wq = qc ? wq1 : wq0;
#pragma unroll
      for (int ni = 0; ni < 4; ++ni) {
        float p0 = exp2f(fmaf(s[qc][ni][0], LOG2E, cr[qc]));
        float p1 = exp2f(fmaf(s[qc][ni][1], LOG2E, cr[qc]));
        float p2 = exp2f(fmaf(s[qc][ni][2], LOG2E, cr[qc]));
        float p3 = exp2f(fmaf(s[qc][ni][3], LOG2E, cr[qc]));
        f32x4 pv4 = {p0, p1, p2, p3};
        __builtin_nontemporal_store(pv4, (f32x4*)(wq + kv0 + ni * 16 + 4 * gq));
        pk2[qc][ni][0] = (unsigned)f2bf(p0) | ((unsigned)f2bf(p1) << 16);
        pk2[qc][ni][1] = (unsigned)f2bf(p2) | ((unsigned)f2bf(p3) << 16);
      }
    }
    // assemble pf per (qc,kk) via shfl; vf read ONCE feeds both q-halves
#pragma unroll
    for (int kk = 0; kk < 2; ++kk) {
      bf8 pfq[2];
#pragma unroll
      for (int qc = 0; qc < 2; ++qc) {
        unsigned xa0 = __shfl(pk2[qc][2 * kk][0], srcA), xa1 = __shfl(pk2[qc][2 * kk][1], srcA);
        unsigned ya0 = __shfl(pk2[qc][2 * kk + 1][0], srcA), ya1 = __shfl(pk2[qc][2 * kk + 1][1], srcA);
        unsigned xb0 = __shfl(pk2[qc][2 * kk][0], srcB), xb1 = __shfl(pk2[qc][2 * kk][1], srcB);
        unsigned yb0 = __shfl(pk2[qc][2 * kk + 1][0], srcB), yb1 = __shfl(pk2[qc][2 * kk + 1][1], srcB);
        u32x4 pf32 = { hi ? ya0 : xa0, hi ? ya1 : xa1, hi ? yb0 : xb0, hi ? yb1 : xb1 };
        pfq[qc] = __builtin_bit_cast(bf8, pf32);
      }
      __builtin_amdgcn_s_setprio(1);
#pragma unroll
      for (int c = 0; c < 8; ++c) {
        bf8 vf = *(const bf8*)&Vs[cur][(c * 16 + lr) * 64 + ((kk * 32 + lk) ^ rsw)];
        oacc[0][c] = mfma16(pfq[0], vf, oacc[0][c]);
        oacc[1][c] = mfma16(pfq[1], vf, oacc[1][c]);
      }
      __builtin_amdgcn_s_setprio(0);
    }
    // drain the 8 prefetch loads; leave the 8 newest (stores) in flight
    asm volatile("s_waitcnt vmcnt(8)" ::: "memory");
    barrier_hard();
  }

  // epilogue: AO [B, Lq, D] bf16 (rows q = w*32 + qc*16 + 4*gq + r)
#pragma unroll
  for (int qc = 0; qc < 2; ++qc)
#pragma unroll
    for (int c = 0; c < 8; ++c)
#pragma unroll
      for (int r = 0; r < 4; ++r)
        AO[((size_t)b * LQ + q0 + w * 32 + qc * 16 + 4 * gq + r) * DD + h * HDm + c * 16 + lr] =
            f2bf(oacc[qc][c][r]);
}

// ---------------------------------------------------------------------------
extern "C" void kernel_launch(void* const* d_in, const int* in_sizes, int n_in,
                              void* d_out, int out_size, void* d_ws, size_t ws_size,
                              hipStream_t stream) {
  const float* hs   = (const float*)d_in[0];
  const float* cas  = (const float*)d_in[1];
  const float* q_w  = (const float*)d_in[2];
  const float* q_b  = (const float*)d_in[3];
  const float* k_w  = (const float*)d_in[4];
  const float* k_b  = (const float*)d_in[5];
  const float* v_w  = (const float*)d_in[6];
  const float* v_b  = (const float*)d_in[7];
  const float* o_w  = (const float*)d_in[8];
  const float* o_b  = (const float*)d_in[9];
  const float* qn_g = (const float*)d_in[10];
  const float* qn_b = (const float*)d_in[11];
  const float* kn_g = (const float*)d_in[12];
  const float* kn_b = (const float*)d_in[13];

  float* out_attn = (float*)d_out;
  float* out_w    = out_attn + (size_t)BB * LQ * DD;

  constexpr size_t SZ_Q  = (size_t)BB * LQ * DD * 2;
  constexpr size_t SZ_KV = (size_t)BB * LKV * DD * 2;
  constexpr size_t SZ_W  = (size_t)DD * DD * 2;
  char* p = (char*)d_ws;
  u16* hsb  = (u16*)p;              p += SZ_Q;
  u16* casb = (u16*)p;              p += SZ_KV;
  u16* qwb  = (u16*)p;              p += SZ_W;
  u16* kwb  = (u16*)p;              p += SZ_W;
  u16* vwb  = (u16*)p;              p += SZ_W;
  u16* owb  = (u16*)p;              p += SZ_W;
  u16* Qp   = (u16*)p;              p += SZ_Q;
  u16* Kp   = (u16*)p;              p += SZ_KV;
  u16* Vtp  = (u16*)p;              p += SZ_KV;
  u16* AO   = (u16*)p;              p += SZ_Q;

  auto cvt = [&](const float* src, u16* dst, size_t n) {
    int n4 = (int)(n / 4);
    k_cvt<<<dim3((n4 + 255) / 256), dim3(256), 0, stream>>>(
        (const float4*)src, (ushort4*)dst, n4);
  };
  cvt(hs,  hsb,  (size_t)BB * LQ * DD);
  cvt(cas, casb, (size_t)BB * LKV * DD);
  cvt(q_w, qwb, (size_t)DD * DD);
  cvt(k_w, kwb, (size_t)DD * DD);
  cvt(v_w, vwb, (size_t)DD * DD);
  cvt(o_w, owb, (size_t)DD * DD);

  // projections; LN fused for Q (with ATTN_SCALE) and K; V writes transposed
  k_gemm_nt<3><<<dim3(BB * LQ / 256, DD / 128), dim3(512), 0, stream>>>(
      hsb, qwb, q_b, qn_g, qn_b, Qp, BB * LQ, DD, DD);
  k_gemm_nt<2><<<dim3(BB * LKV / 256, DD / 128), dim3(512), 0, stream>>>(
      casb, kwb, k_b, kn_g, kn_b, Kp, BB * LKV, DD, DD);
  k_gemm_nt<4><<<dim3(BB * LKV / 256, DD / 128), dim3(512), 0, stream>>>(
      casb, vwb, v_b, nullptr, nullptr, Vtp, BB * LKV, DD, DD);

  k_attn<<<dim3(LQ / 128 * BB * NH), dim3(256), 0, stream>>>(Qp, Kp, Vtp, out_w, AO);

  k_gemm_nt<1><<<dim3(BB * LQ / 256, DD / 128), dim3(512), 0, stream>>>(
      AO, owb, o_b, nullptr, nullptr, out_attn, BB * LQ, DD, DD);
}

// Round 9
// 796.172 us; speedup vs baseline: 1.0029x; 1.0029x over previous
//
#include <hip/hip_runtime.h>
#include <cstdint>
#include <cstddef>

using u16 = unsigned short;
using f32x4 = __attribute__((ext_vector_type(4))) float;
using bf8   = __attribute__((ext_vector_type(8))) short;   // 8 bf16 in 4 VGPRs
using u32x4 = __attribute__((ext_vector_type(4))) unsigned;

#define DEVFN __device__ __forceinline__

constexpr int BB  = 2;
constexpr int LQ  = 2048;
constexpr int LKV = 4096;
constexpr int DD  = 2048;
constexpr int NH  = 16;
constexpr int HDm = 128;
constexpr float ATTN_SCALE = 0.08838834764831845f;  // 128^-0.5
constexpr float LN_EPS = 1e-6f;
// softmax fixed shift: LN guarantees |s| <= ||q*scale||*||k|| = 1*sqrt(128) ~ 11.4
constexpr float LOG2E  = 1.4426950408889634f;
constexpr float SHIFT2 = 17.312340490667562f;       // 12.0 * log2(e)

DEVFN u16 f2bf(float f) {
  unsigned u = __builtin_bit_cast(unsigned, f);
  u += 0x7fffu + ((u >> 16) & 1u);          // RNE
  return (u16)(u >> 16);
}
DEVFN float bf2f(u16 h) { return __builtin_bit_cast(float, (unsigned)h << 16); }
DEVFN f32x4 mfma16(bf8 a, bf8 b, f32x4 c) {
  return __builtin_amdgcn_mfma_f32_16x16x32_bf16(a, b, c, 0, 0, 0);
}
// async global->LDS, 16B/lane, lane i lands at lds + i*16 (wave-uniform lds base)
DEVFN void gl16(const void* g, void* l) {
  __builtin_amdgcn_global_load_lds(
      (const __attribute__((address_space(1))) void*)g,
      (__attribute__((address_space(3))) void*)l, 16, 0, 0);
}
DEVFN void barrier_hard() {                 // raw barrier + scheduler fence
  __builtin_amdgcn_s_barrier();
  __builtin_amdgcn_sched_barrier(0);
}

// ---------------- fused f32 -> bf16 convert, ALL segments in one launch ----
struct C6 {
  const float4* s[6];
  ushort4* d[6];
  unsigned off[7];                          // prefix sums in float4 units
};
__global__ __launch_bounds__(256) void k_cvt6(C6 a) {
  unsigned gi = blockIdx.x * 256 + threadIdx.x;
  if (gi >= a.off[6]) return;
  int seg = 0;
#pragma unroll
  for (int i = 1; i < 6; ++i) seg += (gi >= a.off[i]);
  unsigned j = gi - a.off[seg];
  float4 v = a.s[seg][j];
  ushort4 o;
  o.x = f2bf(v.x); o.y = f2bf(v.y); o.z = f2bf(v.z); o.w = f2bf(v.w);
  a.d[seg][j] = o;
}

// ---------------- bf16 NT GEMM: Y[M,N] = X[M,K] * W[N,K]^T + bias[N] -------
// (R6-verified) 128x128 tile, BK=64, 4 waves, gl16 staging + XOR swizzle.
// MODE: 1 = f32 out (nontemporal); 2 = bf16 + per-head LN;
//       3 = bf16 + per-head LN + ATTN_SCALE;
//       4 = bf16 TRANSPOSED per-head out -> Y[bh][hd][kv]  (fused V-transpose)
template <int MODE>
__global__ __launch_bounds__(256) void k_gemm_nt(const u16* __restrict__ X,
                                                 const u16* __restrict__ Wt,
                                                 const float* __restrict__ bias,
                                                 const float* __restrict__ lng,
                                                 const float* __restrict__ lnb,
                                                 void* __restrict__ Y,
                                                 int M, int N, int K) {
  __shared__ __align__(16) u16 Sh[2][128 * 64];   // As | Bs ; reused as T[128][128]
  __shared__ float Sm[2][128], Sq[2][128];
  u16* As = Sh[0];
  u16* Bs = Sh[1];
  const int tid = threadIdx.x;
  const int w = tid >> 6, l = tid & 63;
  const int m0 = blockIdx.x * 128, n0 = blockIdx.y * 128;
  const int wr = w >> 1, wc = w & 1;
  const int lr = l & 15, lk = (l >> 4) * 8;
  const int rsw = (l & 7) << 3;               // read-side swizzle (u16 units)
  const int srow = l >> 3;
  const int scb = (l & 7) * 16;
  f32x4 acc[4][4] = {};

  for (int k0 = 0; k0 < K; k0 += 64) {
#pragma unroll
    for (int i = 0; i < 4; ++i) {
      int rbase = w * 32 + i * 8;
      int row = rbase + srow;
      int cb = scb ^ ((row & 7) << 4);        // inverse-swizzled source col (bytes)
      gl16((const char*)&X[(size_t)(m0 + row) * K + k0] + cb, &As[rbase * 64]);
      gl16((const char*)&Wt[(size_t)(n0 + row) * K + k0] + cb, &Bs[rbase * 64]);
    }
    __syncthreads();
    bf8 af[4][2], bfr[4][2];
#pragma unroll
    for (int mi = 0; mi < 4; ++mi)
#pragma unroll
      for (int kk = 0; kk < 2; ++kk)
        af[mi][kk] = *(const bf8*)&As[(wr * 64 + mi * 16 + lr) * 64 + ((kk * 32 + lk) ^ rsw)];
#pragma unroll
    for (int ni = 0; ni < 4; ++ni)
#pragma unroll
      for (int kk = 0; kk < 2; ++kk)
        bfr[ni][kk] = *(const bf8*)&Bs[(wc * 64 + ni * 16 + lr) * 64 + ((kk * 32 + lk) ^ rsw)];
#pragma unroll
    for (int kk = 0; kk < 2; ++kk)
#pragma unroll
      for (int mi = 0; mi < 4; ++mi)
#pragma unroll
        for (int ni = 0; ni < 4; ++ni)
          acc[mi][ni] = mfma16(af[mi][kk], bfr[ni][kk], acc[mi][ni]);
    __syncthreads();
  }
  const int lrg = (l >> 4) * 4;

  // bias (pre-LN, matching reference: LN(x@W^T + b))
  float bv[4];
#pragma unroll
  for (int ni = 0; ni < 4; ++ni) bv[ni] = bias[n0 + wc * 64 + ni * 16 + lr];
#pragma unroll
  for (int mi = 0; mi < 4; ++mi)
#pragma unroll
    for (int ni = 0; ni < 4; ++ni)
#pragma unroll
      for (int r = 0; r < 4; ++r) acc[mi][ni][r] += bv[ni];

  if constexpr (MODE == 2 || MODE == 3) {
#pragma unroll
    for (int mi = 0; mi < 4; ++mi) {
#pragma unroll
      for (int r = 0; r < 4; ++r) {
        float ps = 0.f, pq = 0.f;
#pragma unroll
        for (int ni = 0; ni < 4; ++ni) {
          float v = acc[mi][ni][r];
          ps += v; pq += v * v;
        }
#pragma unroll
        for (int m = 1; m < 16; m <<= 1) {
          ps += __shfl_xor(ps, m);
          pq += __shfl_xor(pq, m);
        }
        if (lr == 0) {
          int rl = wr * 64 + mi * 16 + lrg + r;
          Sm[wc][rl] = ps; Sq[wc][rl] = pq;
        }
      }
    }
    __syncthreads();
    float gv[4], bbv[4];
#pragma unroll
    for (int ni = 0; ni < 4; ++ni) {
      int c = wc * 64 + ni * 16 + lr;          // col within head (n-tile aligned)
      gv[ni] = lng[c]; bbv[ni] = lnb[c];
    }
#pragma unroll
    for (int mi = 0; mi < 4; ++mi)
#pragma unroll
      for (int r = 0; r < 4; ++r) {
        int rl = wr * 64 + mi * 16 + lrg + r;
        float mean = (Sm[0][rl] + Sm[1][rl]) * (1.f / 128.f);
        float var  = (Sq[0][rl] + Sq[1][rl]) * (1.f / 128.f) - mean * mean;
        float rs = rsqrtf(var + LN_EPS);
#pragma unroll
        for (int ni = 0; ni < 4; ++ni) {
          float o = (acc[mi][ni][r] - mean) * rs * gv[ni] + bbv[ni];
          if (MODE == 3) o *= ATTN_SCALE;
          acc[mi][ni][r] = o;
        }
      }
  }

  if constexpr (MODE == 4) {
    u16* T = &Sh[0][0];                        // 128*128 u16 = 32 KB
#pragma unroll
    for (int mi = 0; mi < 4; ++mi)
#pragma unroll
      for (int ni = 0; ni < 4; ++ni)
#pragma unroll
        for (int r = 0; r < 4; ++r) {
          int mrow = wr * 64 + mi * 16 + lrg + r;
          int ncol = wc * 64 + ni * 16 + lr;
          T[mrow * 128 + (ncol ^ ((mrow & 7) << 3))] = f2bf(acc[mi][ni][r]);
        }
    __syncthreads();
    int hd = tid >> 1, half = tid & 1;
    int bq = m0 >> 12;                          // m = b*LKV + kv, LKV=4096
    int kvb = (m0 & (LKV - 1)) + half * 64;
    int hh = n0 >> 7;                           // n-tile == head
    u16* vout = (u16*)Y + ((size_t)(bq * NH + hh) * HDm + hd) * LKV + kvb;
#pragma unroll
    for (int j8 = 0; j8 < 8; ++j8) {
      u16 tmp[8] __attribute__((aligned(16)));
#pragma unroll
      for (int j = 0; j < 8; ++j) {
        int kv = half * 64 + j8 * 8 + j;
        tmp[j] = T[kv * 128 + (hd ^ ((kv & 7) << 3))];
      }
      *(int4*)&vout[j8 * 8] = *(const int4*)tmp;
    }
    return;
  }

#pragma unroll
  for (int ni = 0; ni < 4; ++ni) {
    int n = n0 + wc * 64 + ni * 16 + lr;
#pragma unroll
    for (int mi = 0; mi < 4; ++mi) {
      int mb = m0 + wr * 64 + mi * 16 + lrg;
#pragma unroll
      for (int r = 0; r < 4; ++r) {
        float v = acc[mi][ni][r];
        if constexpr (MODE == 1)
          __builtin_nontemporal_store(v, &((float*)Y)[(size_t)(mb + r) * N + n]);
        else
          ((u16*)Y)[(size_t)(mb + r) * N + n] = f2bf(v);
      }
    }
  }
}

// ---------------- pass A: softmax row-offset kernel ------------------------
// 256 blocks (8 q-tiles of 256 x 32 bh), 8 waves x 32 q-rows (dual qf: each
// K fragment read feeds 2 MFMAs). kv-tile 128, dbuf 2x32KB -> 2 blocks/CU.
// Writes cr[bh][q] = -(SHIFT2 + log2(sum_kv exp2(s*log2e - SHIFT2))).
__global__ __launch_bounds__(512, 4) void k_sums(const u16* __restrict__ Qp,
                                                 const u16* __restrict__ Kp,
                                                 float* __restrict__ crg) {
  const int g = blockIdx.x;                 // 256 blocks, 8 XCDs, 32 each
  const int work = (g & 7) * 32 + (g >> 3);
  const int bh = work >> 3;
  const int b = bh >> 4, h = bh & 15;
  const int q0 = (work & 7) * 256;
  const int tid = threadIdx.x, w = tid >> 6, l = tid & 63;
  const int lr = l & 15, lk = (l >> 4) * 8;
  const int rsw = (l & 7) << 3;
  __shared__ __align__(16) u16 Kt[2][128 * 128];   // 32 KB each

  bf8 qf[2][4];
#pragma unroll
  for (int qc = 0; qc < 2; ++qc) {
    const u16* qb = &Qp[((size_t)b * LQ + q0 + w * 32 + qc * 16 + lr) * DD + h * HDm];
#pragma unroll
    for (int kc = 0; kc < 4; ++kc) qf[qc][kc] = *(const bf8*)(qb + kc * 32 + lk);
  }
  const u16* Kb = Kp + (size_t)b * LKV * DD + h * HDm;

  auto stage = [&](int buf, int kv0) {      // 128 rows x 256 B, 4 gl16/wave
#pragma unroll
    for (int i = 0; i < 4; ++i) {
      int rbase = w * 16 + i * 4;
      int row = rbase + (l >> 4);
      int cb = ((l & 15) * 16) ^ ((row & 7) << 4);
      gl16((const char*)(Kb + (size_t)(kv0 + row) * DD) + cb, &Kt[buf][rbase * 128]);
    }
  };

  float lsum[2] = {0.f, 0.f};
  stage(0, 0);
  asm volatile("s_waitcnt vmcnt(0)" ::: "memory");
  barrier_hard();
  for (int t = 0; t < 32; ++t) {
    const int cur = t & 1;
    if (t < 31) stage(cur ^ 1, (t + 1) * 128);
#pragma unroll
    for (int ni = 0; ni < 8; ++ni) {
      f32x4 s0 = {0.f, 0.f, 0.f, 0.f}, s1 = {0.f, 0.f, 0.f, 0.f};
      __builtin_amdgcn_s_setprio(1);
#pragma unroll
      for (int kc = 0; kc < 4; ++kc) {
        bf8 kf = *(const bf8*)&Kt[cur][(ni * 16 + lr) * 128 + ((kc * 32 + lk) ^ rsw)];
        s0 = mfma16(kf, qf[0][kc], s0);
        s1 = mfma16(kf, qf[1][kc], s1);
      }
      __builtin_amdgcn_s_setprio(0);
#pragma unroll
      for (int r = 0; r < 4; ++r) {
        lsum[0] += exp2f(fmaf(s0[r], LOG2E, -SHIFT2));
        lsum[1] += exp2f(fmaf(s1[r], LOG2E, -SHIFT2));
      }
    }
    asm volatile("s_waitcnt vmcnt(0)" ::: "memory");
    barrier_hard();
  }
#pragma unroll
  for (int qc = 0; qc < 2; ++qc) {
    float v = lsum[qc];
    v += __shfl_xor(v, 16);
    v += __shfl_xor(v, 32);
    if (l < 16)
      crg[(size_t)bh * LQ + q0 + w * 32 + qc * 16 + l] = -(SHIFT2 + __log2f(v));
  }
}

// ---------------- fused attention pass B (swapped-operand QK) --------------
// (R6-verified structure) 512 threads / 8 waves, q-tile 128, kv-tile 64 dbuf.
// P in registers (lane lr owns q-row lr), pf assembled via shfl; Wout f32x4
// nontemporal. Counted vmcnt keeps stores in flight. cr precomputed (k_sums).
__global__ __launch_bounds__(512, 4) void k_attn(const u16* __restrict__ Qp,
                                                 const u16* __restrict__ Kp,
                                                 const u16* __restrict__ Vt,
                                                 const float* __restrict__ crg,
                                                 float* __restrict__ Wout,
                                                 u16* __restrict__ AO) {
  const int g = blockIdx.x;                 // 512 blocks, 8 XCDs, 64 each
  const int work = (g & 7) * 64 + (g >> 3);
  const int bh = work >> 4;
  const int b = bh >> 4, h = bh & 15;
  const int q0 = (work & 15) * 128;
  const int tid = threadIdx.x, w = tid >> 6, l = tid & 63;
  const int lr = l & 15, lk = (l >> 4) * 8;
  const int gq = l >> 4;                    // lane group 0..3 (kv sub-quad)
  const int rsw = (l & 7) << 3;             // read swizzle, u16 units
  __shared__ __align__(16) u16 Ks[2][64 * 128];
  __shared__ __align__(16) u16 Vs[2][128 * 64];

  // hoist Q fragments (B-frag for swapped mfma: col = lr, 8 k-els at kc*32+lk)
  bf8 qf[4];
  {
    const u16* qb = &Qp[((size_t)b * LQ + q0 + w * 16 + lr) * DD + h * HDm];
#pragma unroll
    for (int kc = 0; kc < 4; ++kc) qf[kc] = *(const bf8*)(qb + kc * 32 + lk);
  }
  const float crv = crg[(size_t)bh * LQ + q0 + w * 16 + lr];
  const u16* Kb = Kp + (size_t)b * LKV * DD + h * HDm;   // row stride DD
  const u16* Vb = Vt + (size_t)bh * HDm * LKV;           // row (hd) stride LKV

  auto stageK = [&](int buf, int kv0) {       // 64 rows x 256 B
#pragma unroll
    for (int i = 0; i < 2; ++i) {
      int rbase = i * 32 + w * 4;
      int row = rbase + (l >> 4);
      int cb = ((l & 15) * 16) ^ ((row & 7) << 4);
      gl16((const char*)(Kb + (size_t)(kv0 + row) * DD) + cb, &Ks[buf][rbase * 128]);
    }
  };
  auto stageV = [&](int buf, int kv0) {       // 128 rows x 128 B
#pragma unroll
    for (int i = 0; i < 2; ++i) {
      int rbase = i * 64 + w * 8;
      int row = rbase + (l >> 3);
      int cb = ((l & 7) * 16) ^ ((row & 7) << 4);
      gl16((const char*)(Vb + (size_t)row * LKV + kv0) + cb, &Vs[buf][rbase * 64]);
    }
  };

  f32x4 oacc[8] = {};
  float* wq = Wout + ((size_t)bh * LQ + q0 + w * 16 + lr) * LKV;
  const int srcA = lr + ((gq & 1) << 5);
  const int srcB = srcA + 16;
  const bool hi = (gq >> 1) != 0;

  stageK(0, 0); stageV(0, 0);
  asm volatile("s_waitcnt vmcnt(0)" ::: "memory");
  barrier_hard();
  for (int t = 0; t < 64; ++t) {
    const int cur = t & 1;
    const int kv0 = t * 64;
    if (t < 63) { stageK(cur ^ 1, kv0 + 64); stageV(cur ^ 1, kv0 + 64); }
    // QK swapped: s[ni] rows = kv (ni*16 + 4*gq + r), col = q-row lr
    f32x4 s[4];
    __builtin_amdgcn_s_setprio(1);
#pragma unroll
    for (int ni = 0; ni < 4; ++ni) {
      s[ni] = f32x4{0.f, 0.f, 0.f, 0.f};
#pragma unroll
      for (int kc = 0; kc < 4; ++kc) {
        bf8 kf = *(const bf8*)&Ks[cur][(ni * 16 + lr) * 128 + ((kc * 32 + lk) ^ rsw)];
        s[ni] = mfma16(kf, qf[kc], s[ni]);
      }
    }
    __builtin_amdgcn_s_setprio(0);
    // normalized p: 4 contiguous kv per lane -> f32x4 nontemporal stores
    unsigned pk2[4][2];
#pragma unroll
    for (int ni = 0; ni < 4; ++ni) {
      float p0 = exp2f(fmaf(s[ni][0], LOG2E, crv));
      float p1 = exp2f(fmaf(s[ni][1], LOG2E, crv));
      float p2 = exp2f(fmaf(s[ni][2], LOG2E, crv));
      float p3 = exp2f(fmaf(s[ni][3], LOG2E, crv));
      f32x4 pv4 = {p0, p1, p2, p3};
      __builtin_nontemporal_store(pv4, (f32x4*)(wq + kv0 + ni * 16 + 4 * gq));
      pk2[ni][0] = (unsigned)f2bf(p0) | ((unsigned)f2bf(p1) << 16);
      pk2[ni][1] = (unsigned)f2bf(p2) | ((unsigned)f2bf(p3) << 16);
    }
    // assemble pf (A-frag of PV: q-row lr, 8 kv at kk*32+8*gq) via shfl + PV
#pragma unroll
    for (int kk = 0; kk < 2; ++kk) {
      unsigned xa0 = __shfl(pk2[2 * kk][0], srcA), xa1 = __shfl(pk2[2 * kk][1], srcA);
      unsigned ya0 = __shfl(pk2[2 * kk + 1][0], srcA), ya1 = __shfl(pk2[2 * kk + 1][1], srcA);
      unsigned xb0 = __shfl(pk2[2 * kk][0], srcB), xb1 = __shfl(pk2[2 * kk][1], srcB);
      unsigned yb0 = __shfl(pk2[2 * kk + 1][0], srcB), yb1 = __shfl(pk2[2 * kk + 1][1], srcB);
      u32x4 pf32 = { hi ? ya0 : xa0, hi ? ya1 : xa1, hi ? yb0 : xb0, hi ? yb1 : xb1 };
      bf8 pf = __builtin_bit_cast(bf8, pf32);
      __builtin_amdgcn_s_setprio(1);
#pragma unroll
      for (int c = 0; c < 8; ++c) {
        bf8 vf = *(const bf8*)&Vs[cur][(c * 16 + lr) * 64 + ((kk * 32 + lk) ^ rsw)];
        oacc[c] = mfma16(pf, vf, oacc[c]);
      }
      __builtin_amdgcn_s_setprio(0);
    }
    // drain the 4 prefetch loads; leave the 4 newest (stores) in flight
    asm volatile("s_waitcnt vmcnt(4)" ::: "memory");
    barrier_hard();
  }

  // epilogue: AO [B, Lq, D] bf16 (oacc rows q = 4*gq + r, cols hd = c*16+lr)
#pragma unroll
  for (int c = 0; c < 8; ++c)
#pragma unroll
    for (int r = 0; r < 4; ++r)
      AO[((size_t)b * LQ + q0 + w * 16 + 4 * gq + r) * DD + h * HDm + c * 16 + lr] =
          f2bf(oacc[c][r]);
}

// ---------------------------------------------------------------------------
extern "C" void kernel_launch(void* const* d_in, const int* in_sizes, int n_in,
                              void* d_out, int out_size, void* d_ws, size_t ws_size,
                              hipStream_t stream) {
  const float* hs   = (const float*)d_in[0];
  const float* cas  = (const float*)d_in[1];
  const float* q_w  = (const float*)d_in[2];
  const float* q_b  = (const float*)d_in[3];
  const float* k_w  = (const float*)d_in[4];
  const float* k_b  = (const float*)d_in[5];
  const float* v_w  = (const float*)d_in[6];
  const float* v_b  = (const float*)d_in[7];
  const float* o_w  = (const float*)d_in[8];
  const float* o_b  = (const float*)d_in[9];
  const float* qn_g = (const float*)d_in[10];
  const float* qn_b = (const float*)d_in[11];
  const float* kn_g = (const float*)d_in[12];
  const float* kn_b = (const float*)d_in[13];

  float* out_attn = (float*)d_out;
  float* out_w    = out_attn + (size_t)BB * LQ * DD;

  constexpr size_t SZ_Q  = (size_t)BB * LQ * DD * 2;
  constexpr size_t SZ_KV = (size_t)BB * LKV * DD * 2;
  constexpr size_t SZ_W  = (size_t)DD * DD * 2;
  char* p = (char*)d_ws;
  u16* hsb  = (u16*)p;              p += SZ_Q;
  u16* casb = (u16*)p;              p += SZ_KV;
  u16* qwb  = (u16*)p;              p += SZ_W;
  u16* kwb  = (u16*)p;              p += SZ_W;
  u16* vwb  = (u16*)p;              p += SZ_W;
  u16* owb  = (u16*)p;              p += SZ_W;
  u16* Qp   = (u16*)p;              p += SZ_Q;
  u16* Kp   = (u16*)p;              p += SZ_KV;
  u16* Vtp  = (u16*)p;              p += SZ_KV;
  u16* AO   = (u16*)p;              p += SZ_Q;
  float* crg = (float*)p;           p += (size_t)BB * NH * LQ * 4;

  // 1) all f32->bf16 conversions in one launch
  constexpr unsigned HS4 = BB * LQ * DD / 4;     // 2,097,152
  constexpr unsigned CAS4 = BB * LKV * DD / 4;   // 4,194,304
  constexpr unsigned W4 = DD * DD / 4;           // 1,048,576
  C6 a;
  a.s[0] = (const float4*)hs;  a.d[0] = (ushort4*)hsb;
  a.s[1] = (const float4*)cas; a.d[1] = (ushort4*)casb;
  a.s[2] = (const float4*)q_w; a.d[2] = (ushort4*)qwb;
  a.s[3] = (const float4*)k_w; a.d[3] = (ushort4*)kwb;
  a.s[4] = (const float4*)v_w; a.d[4] = (ushort4*)vwb;
  a.s[5] = (const float4*)o_w; a.d[5] = (ushort4*)owb;
  a.off[0] = 0;
  a.off[1] = HS4;
  a.off[2] = HS4 + CAS4;
  a.off[3] = HS4 + CAS4 + W4;
  a.off[4] = HS4 + CAS4 + 2 * W4;
  a.off[5] = HS4 + CAS4 + 3 * W4;
  a.off[6] = HS4 + CAS4 + 4 * W4;
  k_cvt6<<<dim3((a.off[6] + 255) / 256), dim3(256), 0, stream>>>(a);

  // 2) projections; LN fused for Q (with ATTN_SCALE) and K; V transposed
  k_gemm_nt<3><<<dim3(BB * LQ / 128, DD / 128), dim3(256), 0, stream>>>(
      hsb, qwb, q_b, qn_g, qn_b, Qp, BB * LQ, DD, DD);
  k_gemm_nt<2><<<dim3(BB * LKV / 128, DD / 128), dim3(256), 0, stream>>>(
      casb, kwb, k_b, kn_g, kn_b, Kp, BB * LKV, DD, DD);
  k_gemm_nt<4><<<dim3(BB * LKV / 128, DD / 128), dim3(256), 0, stream>>>(
      casb, vwb, v_b, nullptr, nullptr, Vtp, BB * LKV, DD, DD);

  // 3) softmax row sums (pass A) -> cr offsets
  k_sums<<<dim3(LQ / 256 * BB * NH), dim3(512), 0, stream>>>(Qp, Kp, crg);

  // 4) attention pass B: weights + PV
  k_attn<<<dim3(LQ / 128 * BB * NH), dim3(512), 0, stream>>>(
      Qp, Kp, Vtp, crg, out_w, AO);

  // 5) O projection -> fp32 into d_out
  k_gemm_nt<1><<<dim3(BB * LQ / 128, DD / 128), dim3(256), 0, stream>>>(
      AO, owb, o_b, nullptr, nullptr, out_attn, BB * LQ, DD, DD);
}

// Round 10
// 745.717 us; speedup vs baseline: 1.0708x; 1.0677x over previous
//
#include <hip/hip_runtime.h>
#include <cstdint>
#include <cstddef>

using u16 = unsigned short;
using f32x4 = __attribute__((ext_vector_type(4))) float;
using bf8   = __attribute__((ext_vector_type(8))) short;   // 8 bf16 in 4 VGPRs
using u32x4 = __attribute__((ext_vector_type(4))) unsigned;

#define DEVFN __device__ __forceinline__

constexpr int BB  = 2;
constexpr int LQ  = 2048;
constexpr int LKV = 4096;
constexpr int DD  = 2048;
constexpr int NH  = 16;
constexpr int HDm = 128;
constexpr float ATTN_SCALE = 0.08838834764831845f;  // 128^-0.5
constexpr float LN_EPS = 1e-6f;
// softmax fixed shift: LN guarantees |s| <= ||q*scale||*||k|| = 1*sqrt(128) ~ 11.4
constexpr float LOG2E  = 1.4426950408889634f;
constexpr float SHIFT2 = 17.312340490667562f;       // 12.0 * log2(e)

DEVFN u16 f2bf(float f) {
  unsigned u = __builtin_bit_cast(unsigned, f);
  u += 0x7fffu + ((u >> 16) & 1u);          // RNE
  return (u16)(u >> 16);
}
DEVFN float bf2f(u16 h) { return __builtin_bit_cast(float, (unsigned)h << 16); }
DEVFN f32x4 mfma16(bf8 a, bf8 b, f32x4 c) {
  return __builtin_amdgcn_mfma_f32_16x16x32_bf16(a, b, c, 0, 0, 0);
}
// async global->LDS, 16B/lane, lane i lands at lds + i*16 (wave-uniform lds base)
DEVFN void gl16(const void* g, void* l) {
  __builtin_amdgcn_global_load_lds(
      (const __attribute__((address_space(1))) void*)g,
      (__attribute__((address_space(3))) void*)l, 16, 0, 0);
}
DEVFN void barrier_hard() {                 // raw barrier + scheduler fence
  __builtin_amdgcn_s_barrier();
  __builtin_amdgcn_sched_barrier(0);
}

// ---------------- fused f32 -> bf16 convert, ALL segments in one launch ----
struct C6 {
  const float4* s[6];
  ushort4* d[6];
  unsigned off[7];                          // prefix sums in float4 units
};
__global__ __launch_bounds__(256) void k_cvt6(C6 a) {
  unsigned gi = blockIdx.x * 256 + threadIdx.x;
  if (gi >= a.off[6]) return;
  int seg = 0;
#pragma unroll
  for (int i = 1; i < 6; ++i) seg += (gi >= a.off[i]);
  unsigned j = gi - a.off[seg];
  float4 v = a.s[seg][j];
  ushort4 o;
  o.x = f2bf(v.x); o.y = f2bf(v.y); o.z = f2bf(v.z); o.w = f2bf(v.w);
  a.d[seg][j] = o;
}

// ---------------- bf16 NT GEMM: Y[M,N] = X[M,K] * W[N,K]^T + bias[N] -------
// (R6-verified) 128x128 tile, BK=64, 4 waves, gl16 staging + XOR swizzle.
// MODE: 1 = f32 out (nontemporal); 2 = bf16 + per-head LN;
//       3 = bf16 + per-head LN + ATTN_SCALE;
//       4 = bf16 TRANSPOSED per-head out -> Y[bh][hd][kv]  (fused V-transpose)
template <int MODE>
__global__ __launch_bounds__(256) void k_gemm_nt(const u16* __restrict__ X,
                                                 const u16* __restrict__ Wt,
                                                 const float* __restrict__ bias,
                                                 const float* __restrict__ lng,
                                                 const float* __restrict__ lnb,
                                                 void* __restrict__ Y,
                                                 int M, int N, int K) {
  __shared__ __align__(16) u16 Sh[2][128 * 64];   // As | Bs ; reused as T[128][128]
  __shared__ float Sm[2][128], Sq[2][128];
  u16* As = Sh[0];
  u16* Bs = Sh[1];
  const int tid = threadIdx.x;
  const int w = tid >> 6, l = tid & 63;
  const int m0 = blockIdx.x * 128, n0 = blockIdx.y * 128;
  const int wr = w >> 1, wc = w & 1;
  const int lr = l & 15, lk = (l >> 4) * 8;
  const int rsw = (l & 7) << 3;               // read-side swizzle (u16 units)
  const int srow = l >> 3;
  const int scb = (l & 7) * 16;
  f32x4 acc[4][4] = {};

  for (int k0 = 0; k0 < K; k0 += 64) {
#pragma unroll
    for (int i = 0; i < 4; ++i) {
      int rbase = w * 32 + i * 8;
      int row = rbase + srow;
      int cb = scb ^ ((row & 7) << 4);        // inverse-swizzled source col (bytes)
      gl16((const char*)&X[(size_t)(m0 + row) * K + k0] + cb, &As[rbase * 64]);
      gl16((const char*)&Wt[(size_t)(n0 + row) * K + k0] + cb, &Bs[rbase * 64]);
    }
    __syncthreads();
    bf8 af[4][2], bfr[4][2];
#pragma unroll
    for (int mi = 0; mi < 4; ++mi)
#pragma unroll
      for (int kk = 0; kk < 2; ++kk)
        af[mi][kk] = *(const bf8*)&As[(wr * 64 + mi * 16 + lr) * 64 + ((kk * 32 + lk) ^ rsw)];
#pragma unroll
    for (int ni = 0; ni < 4; ++ni)
#pragma unroll
      for (int kk = 0; kk < 2; ++kk)
        bfr[ni][kk] = *(const bf8*)&Bs[(wc * 64 + ni * 16 + lr) * 64 + ((kk * 32 + lk) ^ rsw)];
#pragma unroll
    for (int kk = 0; kk < 2; ++kk)
#pragma unroll
      for (int mi = 0; mi < 4; ++mi)
#pragma unroll
        for (int ni = 0; ni < 4; ++ni)
          acc[mi][ni] = mfma16(af[mi][kk], bfr[ni][kk], acc[mi][ni]);
    __syncthreads();
  }
  const int lrg = (l >> 4) * 4;

  // bias (pre-LN, matching reference: LN(x@W^T + b))
  float bv[4];
#pragma unroll
  for (int ni = 0; ni < 4; ++ni) bv[ni] = bias[n0 + wc * 64 + ni * 16 + lr];
#pragma unroll
  for (int mi = 0; mi < 4; ++mi)
#pragma unroll
    for (int ni = 0; ni < 4; ++ni)
#pragma unroll
      for (int r = 0; r < 4; ++r) acc[mi][ni][r] += bv[ni];

  if constexpr (MODE == 2 || MODE == 3) {
#pragma unroll
    for (int mi = 0; mi < 4; ++mi) {
#pragma unroll
      for (int r = 0; r < 4; ++r) {
        float ps = 0.f, pq = 0.f;
#pragma unroll
        for (int ni = 0; ni < 4; ++ni) {
          float v = acc[mi][ni][r];
          ps += v; pq += v * v;
        }
#pragma unroll
        for (int m = 1; m < 16; m <<= 1) {
          ps += __shfl_xor(ps, m);
          pq += __shfl_xor(pq, m);
        }
        if (lr == 0) {
          int rl = wr * 64 + mi * 16 + lrg + r;
          Sm[wc][rl] = ps; Sq[wc][rl] = pq;
        }
      }
    }
    __syncthreads();
    float gv[4], bbv[4];
#pragma unroll
    for (int ni = 0; ni < 4; ++ni) {
      int c = wc * 64 + ni * 16 + lr;          // col within head (n-tile aligned)
      gv[ni] = lng[c]; bbv[ni] = lnb[c];
    }
#pragma unroll
    for (int mi = 0; mi < 4; ++mi)
#pragma unroll
      for (int r = 0; r < 4; ++r) {
        int rl = wr * 64 + mi * 16 + lrg + r;
        float mean = (Sm[0][rl] + Sm[1][rl]) * (1.f / 128.f);
        float var  = (Sq[0][rl] + Sq[1][rl]) * (1.f / 128.f) - mean * mean;
        float rs = rsqrtf(var + LN_EPS);
#pragma unroll
        for (int ni = 0; ni < 4; ++ni) {
          float o = (acc[mi][ni][r] - mean) * rs * gv[ni] + bbv[ni];
          if (MODE == 3) o *= ATTN_SCALE;
          acc[mi][ni][r] = o;
        }
      }
  }

  if constexpr (MODE == 4) {
    u16* T = &Sh[0][0];                        // 128*128 u16 = 32 KB
#pragma unroll
    for (int mi = 0; mi < 4; ++mi)
#pragma unroll
      for (int ni = 0; ni < 4; ++ni)
#pragma unroll
        for (int r = 0; r < 4; ++r) {
          int mrow = wr * 64 + mi * 16 + lrg + r;
          int ncol = wc * 64 + ni * 16 + lr;
          T[mrow * 128 + (ncol ^ ((mrow & 7) << 3))] = f2bf(acc[mi][ni][r]);
        }
    __syncthreads();
    int hd = tid >> 1, half = tid & 1;
    int bq = m0 >> 12;                          // m = b*LKV + kv, LKV=4096
    int kvb = (m0 & (LKV - 1)) + half * 64;
    int hh = n0 >> 7;                           // n-tile == head
    u16* vout = (u16*)Y + ((size_t)(bq * NH + hh) * HDm + hd) * LKV + kvb;
#pragma unroll
    for (int j8 = 0; j8 < 8; ++j8) {
      u16 tmp[8] __attribute__((aligned(16)));
#pragma unroll
      for (int j = 0; j < 8; ++j) {
        int kv = half * 64 + j8 * 8 + j;
        tmp[j] = T[kv * 128 + (hd ^ ((kv & 7) << 3))];
      }
      *(int4*)&vout[j8 * 8] = *(const int4*)tmp;
    }
    return;
  }

#pragma unroll
  for (int ni = 0; ni < 4; ++ni) {
    int n = n0 + wc * 64 + ni * 16 + lr;
#pragma unroll
    for (int mi = 0; mi < 4; ++mi) {
      int mb = m0 + wr * 64 + mi * 16 + lrg;
#pragma unroll
      for (int r = 0; r < 4; ++r) {
        float v = acc[mi][ni][r];
        if constexpr (MODE == 1)
          __builtin_nontemporal_store(v, &((float*)Y)[(size_t)(mb + r) * N + n]);
        else
          ((u16*)Y)[(size_t)(mb + r) * N + n] = f2bf(v);
      }
    }
  }
}

// ---------------- fused attention (R6-verified, 753 us config) -------------
// 512 threads / 8 waves, q-tile 128. Pass A: kv-tile 128 (Ks+Vs unioned as two
// 32KB dbuf regions), lane-local row sums. Pass B: kv-tile 64, dbuf, P in
// registers (lane lr owns q-row lr), pf assembled via shfl; Wout written as
// f32x4 nontemporal. One barrier + counted vmcnt per iter.
__global__ __launch_bounds__(512, 4) void k_attn(const u16* __restrict__ Qp,
                                                 const u16* __restrict__ Kp,
                                                 const u16* __restrict__ Vt,
                                                 float* __restrict__ Wout,
                                                 u16* __restrict__ AO) {
  const int g = blockIdx.x;                 // 512 blocks, 8 XCDs, 64 each
  const int work = (g & 7) * 64 + (g >> 3);
  const int bh = work >> 4;
  const int b = bh >> 4, h = bh & 15;
  const int q0 = (work & 15) * 128;
  const int tid = threadIdx.x, w = tid >> 6, l = tid & 63;
  const int lr = l & 15, lk = (l >> 4) * 8;
  const int gq = l >> 4;                    // lane group 0..3 (kv sub-quad)
  const int rsw = (l & 7) << 3;             // read swizzle, u16 units
  __shared__ __align__(16) u16 Ks[2][64 * 128];
  __shared__ __align__(16) u16 Vs[2][128 * 64];

  // hoist Q fragments (B-frag for swapped mfma: col = lr, 8 k-els at kc*32+lk)
  bf8 qf[4];
  {
    const u16* qb = &Qp[((size_t)b * LQ + q0 + w * 16 + lr) * DD + h * HDm];
#pragma unroll
    for (int kc = 0; kc < 4; ++kc) qf[kc] = *(const bf8*)(qb + kc * 32 + lk);
  }
  const u16* Kb = Kp + (size_t)b * LKV * DD + h * HDm;   // row stride DD
  const u16* Vb = Vt + (size_t)bh * HDm * LKV;           // row (hd) stride LKV

  // ---- staging helpers
  auto stageK128 = [&](u16* buf, int kv0) {   // 128 rows x 256 B into 32KB region
#pragma unroll
    for (int i = 0; i < 4; ++i) {
      int rbase = i * 32 + w * 4;
      int row = rbase + (l >> 4);
      int cb = ((l & 15) * 16) ^ ((row & 7) << 4);
      gl16((const char*)(Kb + (size_t)(kv0 + row) * DD) + cb, &buf[rbase * 128]);
    }
  };
  auto stageK = [&](int buf, int kv0) {       // 64 rows x 256 B
#pragma unroll
    for (int i = 0; i < 2; ++i) {
      int rbase = i * 32 + w * 4;
      int row = rbase + (l >> 4);
      int cb = ((l & 15) * 16) ^ ((row & 7) << 4);
      gl16((const char*)(Kb + (size_t)(kv0 + row) * DD) + cb, &Ks[buf][rbase * 128]);
    }
  };
  auto stageV = [&](int buf, int kv0) {       // 128 rows x 128 B
#pragma unroll
    for (int i = 0; i < 2; ++i) {
      int rbase = i * 64 + w * 8;
      int row = rbase + (l >> 3);
      int cb = ((l & 7) * 16) ^ ((row & 7) << 4);
      gl16((const char*)(Vb + (size_t)row * LKV + kv0) + cb, &Vs[buf][rbase * 64]);
    }
  };

  // ================= pass A: lane-local row sums, kv-tile 128 ==============
  u16* bufA0 = &Ks[0][0];                    // 32KB region = 128 rows x 128 u16
  u16* bufA1 = &Vs[0][0];
  float lsum = 0.f;
  stageK128(bufA0, 0);
  asm volatile("s_waitcnt vmcnt(0)" ::: "memory");
  barrier_hard();
  for (int t = 0; t < 32; ++t) {
    const u16* kb = (t & 1) ? bufA1 : bufA0;
    if (t < 31) stageK128((t & 1) ? bufA0 : bufA1, (t + 1) * 128);
    f32x4 s8[8];
    __builtin_amdgcn_s_setprio(1);
#pragma unroll
    for (int ni = 0; ni < 8; ++ni) {
      s8[ni] = f32x4{0.f, 0.f, 0.f, 0.f};
#pragma unroll
      for (int kc = 0; kc < 4; ++kc) {
        bf8 kf = *(const bf8*)&kb[(ni * 16 + lr) * 128 + ((kc * 32 + lk) ^ rsw)];
        s8[ni] = mfma16(kf, qf[kc], s8[ni]);
      }
    }
    __builtin_amdgcn_s_setprio(0);
#pragma unroll
    for (int ni = 0; ni < 8; ++ni)
#pragma unroll
      for (int r = 0; r < 4; ++r)
        lsum += exp2f(fmaf(s8[ni][r], LOG2E, -SHIFT2));
    asm volatile("s_waitcnt vmcnt(0)" ::: "memory");  // next tile staged
    barrier_hard();
  }
  // lane lr holds partials of q-row lr; combine the 4 lane-groups
  lsum += __shfl_xor(lsum, 16);
  lsum += __shfl_xor(lsum, 32);
  const float cr = -(SHIFT2 + __log2f(lsum));   // exp2(s*log2e + cr) = p/sum

  // ================= pass B: weights + PV, kv-tile 64 =======================
  f32x4 oacc[8] = {};
  float* wq = Wout + ((size_t)bh * LQ + q0 + w * 16 + lr) * LKV;
  const int srcA = lr + ((gq & 1) << 5);
  const int srcB = srcA + 16;
  const bool hi = (gq >> 1) != 0;

  stageK(0, 0); stageV(0, 0);
  asm volatile("s_waitcnt vmcnt(0)" ::: "memory");
  barrier_hard();
  for (int t = 0; t < 64; ++t) {
    const int cur = t & 1;
    const int kv0 = t * 64;
    if (t < 63) { stageK(cur ^ 1, kv0 + 64); stageV(cur ^ 1, kv0 + 64); }
    // QK swapped: s[ni] rows = kv (ni*16 + 4*gq + r), col = q-row lr
    f32x4 s[4];
    __builtin_amdgcn_s_setprio(1);
#pragma unroll
    for (int ni = 0; ni < 4; ++ni) {
      s[ni] = f32x4{0.f, 0.f, 0.f, 0.f};
#pragma unroll
      for (int kc = 0; kc < 4; ++kc) {
        bf8 kf = *(const bf8*)&Ks[cur][(ni * 16 + lr) * 128 + ((kc * 32 + lk) ^ rsw)];
        s[ni] = mfma16(kf, qf[kc], s[ni]);
      }
    }
    __builtin_amdgcn_s_setprio(0);
    // normalized p: 4 contiguous kv per lane -> f32x4 nontemporal stores
    unsigned pk2[4][2];
#pragma unroll
    for (int ni = 0; ni < 4; ++ni) {
      float p0 = exp2f(fmaf(s[ni][0], LOG2E, cr));
      float p1 = exp2f(fmaf(s[ni][1], LOG2E, cr));
      float p2 = exp2f(fmaf(s[ni][2], LOG2E, cr));
      float p3 = exp2f(fmaf(s[ni][3], LOG2E, cr));
      f32x4 pv4 = {p0, p1, p2, p3};
      __builtin_nontemporal_store(pv4, (f32x4*)(wq + kv0 + ni * 16 + 4 * gq));
      pk2[ni][0] = (unsigned)f2bf(p0) | ((unsigned)f2bf(p1) << 16);
      pk2[ni][1] = (unsigned)f2bf(p2) | ((unsigned)f2bf(p3) << 16);
    }
    // assemble pf (A-frag of PV: q-row lr, 8 kv at kk*32+8*gq) via shfl + PV
#pragma unroll
    for (int kk = 0; kk < 2; ++kk) {
      unsigned xa0 = __shfl(pk2[2 * kk][0], srcA), xa1 = __shfl(pk2[2 * kk][1], srcA);
      unsigned ya0 = __shfl(pk2[2 * kk + 1][0], srcA), ya1 = __shfl(pk2[2 * kk + 1][1], srcA);
      unsigned xb0 = __shfl(pk2[2 * kk][0], srcB), xb1 = __shfl(pk2[2 * kk][1], srcB);
      unsigned yb0 = __shfl(pk2[2 * kk + 1][0], srcB), yb1 = __shfl(pk2[2 * kk + 1][1], srcB);
      u32x4 pf32 = { hi ? ya0 : xa0, hi ? ya1 : xa1, hi ? yb0 : xb0, hi ? yb1 : xb1 };
      bf8 pf = __builtin_bit_cast(bf8, pf32);
      __builtin_amdgcn_s_setprio(1);
#pragma unroll
      for (int c = 0; c < 8; ++c) {
        bf8 vf = *(const bf8*)&Vs[cur][(c * 16 + lr) * 64 + ((kk * 32 + lk) ^ rsw)];
        oacc[c] = mfma16(pf, vf, oacc[c]);
      }
      __builtin_amdgcn_s_setprio(0);
    }
    // drain the 4 prefetch loads; leave the 4 newest (stores) in flight
    asm volatile("s_waitcnt vmcnt(4)" ::: "memory");
    barrier_hard();
  }

  // epilogue: AO [B, Lq, D] bf16 (oacc rows q = 4*gq + r, cols hd = c*16+lr)
#pragma unroll
  for (int c = 0; c < 8; ++c)
#pragma unroll
    for (int r = 0; r < 4; ++r)
      AO[((size_t)b * LQ + q0 + w * 16 + 4 * gq + r) * DD + h * HDm + c * 16 + lr] =
          f2bf(oacc[c][r]);
}

// ---------------------------------------------------------------------------
extern "C" void kernel_launch(void* const* d_in, const int* in_sizes, int n_in,
                              void* d_out, int out_size, void* d_ws, size_t ws_size,
                              hipStream_t stream) {
  const float* hs   = (const float*)d_in[0];
  const float* cas  = (const float*)d_in[1];
  const float* q_w  = (const float*)d_in[2];
  const float* q_b  = (const float*)d_in[3];
  const float* k_w  = (const float*)d_in[4];
  const float* k_b  = (const float*)d_in[5];
  const float* v_w  = (const float*)d_in[6];
  const float* v_b  = (const float*)d_in[7];
  const float* o_w  = (const float*)d_in[8];
  const float* o_b  = (const float*)d_in[9];
  const float* qn_g = (const float*)d_in[10];
  const float* qn_b = (const float*)d_in[11];
  const float* kn_g = (const float*)d_in[12];
  const float* kn_b = (const float*)d_in[13];

  float* out_attn = (float*)d_out;
  float* out_w    = out_attn + (size_t)BB * LQ * DD;

  constexpr size_t SZ_Q  = (size_t)BB * LQ * DD * 2;
  constexpr size_t SZ_KV = (size_t)BB * LKV * DD * 2;
  constexpr size_t SZ_W  = (size_t)DD * DD * 2;
  char* p = (char*)d_ws;
  u16* hsb  = (u16*)p;              p += SZ_Q;
  u16* casb = (u16*)p;              p += SZ_KV;
  u16* qwb  = (u16*)p;              p += SZ_W;
  u16* kwb  = (u16*)p;              p += SZ_W;
  u16* vwb  = (u16*)p;              p += SZ_W;
  u16* owb  = (u16*)p;              p += SZ_W;
  u16* Qp   = (u16*)p;              p += SZ_Q;
  u16* Kp   = (u16*)p;              p += SZ_KV;
  u16* Vtp  = (u16*)p;              p += SZ_KV;
  u16* AO   = (u16*)p;              p += SZ_Q;

  // 1) all f32->bf16 conversions in one launch
  constexpr unsigned HS4 = BB * LQ * DD / 4;
  constexpr unsigned CAS4 = BB * LKV * DD / 4;
  constexpr unsigned W4 = DD * DD / 4;
  C6 a;
  a.s[0] = (const float4*)hs;  a.d[0] = (ushort4*)hsb;
  a.s[1] = (const float4*)cas; a.d[1] = (ushort4*)casb;
  a.s[2] = (const float4*)q_w; a.d[2] = (ushort4*)qwb;
  a.s[3] = (const float4*)k_w; a.d[3] = (ushort4*)kwb;
  a.s[4] = (const float4*)v_w; a.d[4] = (ushort4*)vwb;
  a.s[5] = (const float4*)o_w; a.d[5] = (ushort4*)owb;
  a.off[0] = 0;
  a.off[1] = HS4;
  a.off[2] = HS4 + CAS4;
  a.off[3] = HS4 + CAS4 + W4;
  a.off[4] = HS4 + CAS4 + 2 * W4;
  a.off[5] = HS4 + CAS4 + 3 * W4;
  a.off[6] = HS4 + CAS4 + 4 * W4;
  k_cvt6<<<dim3((a.off[6] + 255) / 256), dim3(256), 0, stream>>>(a);

  // 2) projections; LN fused for Q (with ATTN_SCALE) and K; V writes transposed
  k_gemm_nt<3><<<dim3(BB * LQ / 128, DD / 128), dim3(256), 0, stream>>>(
      hsb, qwb, q_b, qn_g, qn_b, Qp, BB * LQ, DD, DD);
  k_gemm_nt<2><<<dim3(BB * LKV / 128, DD / 128), dim3(256), 0, stream>>>(
      casb, kwb, k_b, kn_g, kn_b, Kp, BB * LKV, DD, DD);
  k_gemm_nt<4><<<dim3(BB * LKV / 128, DD / 128), dim3(256), 0, stream>>>(
      casb, vwb, v_b, nullptr, nullptr, Vtp, BB * LKV, DD, DD);

  // 3) fused attention (pass A sums + pass B weights/PV, R6 structure)
  k_attn<<<dim3(LQ / 128 * BB * NH), dim3(512), 0, stream>>>(Qp, Kp, Vtp, out_w, AO);

  // 4) O projection -> fp32 into d_out
  k_gemm_nt<1><<<dim3(BB * LQ / 128, DD / 128), dim3(256), 0, stream>>>(
      AO, owb, o_b, nullptr, nullptr, out_attn, BB * LQ, DD, DD);
}